// Round 2
// baseline (215.063 us; speedup 1.0000x reference)
//
#include <hip/hip_runtime.h>
#include <hip/hip_bf16.h>

typedef __attribute__((ext_vector_type(4))) float f32x4;
typedef __attribute__((ext_vector_type(8))) short s16x8;

__device__ inline short to_bf16(float f) {
  union { float f; unsigned u; } c; c.f = f;
  unsigned u = c.u;
  u += 0x7fffu + ((u >> 16) & 1u);   // round-to-nearest-even
  return (short)(u >> 16);
}

__device__ inline s16x8 pack8(f32x4 a, f32x4 b) {
  s16x8 r;
  r[0] = to_bf16(a[0]); r[1] = to_bf16(a[1]); r[2] = to_bf16(a[2]); r[3] = to_bf16(a[3]);
  r[4] = to_bf16(b[0]); r[5] = to_bf16(b[1]); r[6] = to_bf16(b[2]); r[7] = to_bf16(b[3]);
  return r;
}

#define BPW 2   // blocks per workgroup; 1024 wgs * 2 = 2048 blocks

// Each wave owns one output quadrant (ky,kx) of its block: 4 m-tiles of weights
// (32 VGPRs, not 128) -> fits 4 waves/SIMD. Wave processes all 16 rows.
__global__ __launch_bounds__(256, 4)
void sparse_deconv_kernel(const float* __restrict__ in, const float* __restrict__ mask,
                          const float* __restrict__ kern, const float* __restrict__ bias,
                          float* __restrict__ out) {
  const int tid = threadIdx.x;
  const int w  = tid >> 6;            // wave 0..3 -> quadrant
  const int l  = tid & 63;
  const int lm = l & 15;
  const int lg = l >> 4;
  const int ky = w >> 1;
  const int kx = w & 1;

  // Weights for this wave's 4 m-tiles: mtot = w*4 + ft  (kernel flat [256][64])
  s16x8 wf[4][2];
#pragma unroll
  for (int ft = 0; ft < 4; ++ft) {
#pragma unroll
    for (int kf = 0; kf < 2; ++kf) {
      const float* p = kern + (((w * 4 + ft) * 16 + lm) * 64 + kf * 32 + lg * 8);
      wf[ft][kf] = pack8(*(const f32x4*)p, *(const f32x4*)(p + 4));
    }
  }

  // bias fragments matching C/D row layout: f = ft*16 + lg*4 + j
  f32x4 bv[4];
#pragma unroll
  for (int ft = 0; ft < 4; ++ft)
    bv[ft] = *(const f32x4*)(bias + ft * 16 + lg * 4);

  for (int kb = 0; kb < BPW; ++kb) {
    const int b  = blockIdx.x * BPW + kb;   // 0..2047
    const int n  = b >> 8;
    const int by = (b >> 4) & 15;
    const int bx = b & 15;

    // per-block mask max (redundant per wave; no barriers anywhere)
    const float* mp = mask + ((n * 256 + by * 16) * 256 + bx * 16);
    float mv = 0.0f;
#pragma unroll
    for (int i = 0; i < 4; ++i) {
      const int idx = i * 64 + l;
      mv = fmaxf(mv, mp[(idx >> 4) * 256 + (idx & 15)]);
    }
#pragma unroll
    for (int off = 32; off; off >>= 1)
      mv = fmaxf(mv, __shfl_xor(mv, off));
    const bool active = mv > 0.5f;

    // lane's input pixel column: gx = bx*16 + lm; channels lg*8..
    const float* ibase = in + (((n * 256 + by * 16) * 256) + bx * 16 + lm) * 64 + lg * 8;
    // lane's output pixel: (by*32 + 2y + ky, bx*32 + 2*lm + kx), channel lg*4 (+ft*16)
    float* obase = out + (((n * 512 + by * 32 + ky) * 512) + bx * 32 + 2 * lm + kx) * 64 + lg * 4;

    if (active) {
      f32x4 t0, t1, t2, t3;
      {
        const float* p = ibase;
        t0 = *(const f32x4*)p;        t1 = *(const f32x4*)(p + 4);
        t2 = *(const f32x4*)(p + 32); t3 = *(const f32x4*)(p + 36);
      }
      s16x8 xf0 = pack8(t0, t1), xf1 = pack8(t2, t3);
#pragma unroll 4
      for (int y = 0; y < 16; ++y) {
        // prefetch next row before the MFMA phase
        if (y < 15) {
          const float* p = ibase + (y + 1) * (256 * 64);
          t0 = *(const f32x4*)p;        t1 = *(const f32x4*)(p + 4);
          t2 = *(const f32x4*)(p + 32); t3 = *(const f32x4*)(p + 36);
        }
        float* ob = obase + y * (2 * 512 * 64);
#pragma unroll
        for (int ft = 0; ft < 4; ++ft) {
          f32x4 acc = bv[ft];   // bias folded into accumulator init
          acc = __builtin_amdgcn_mfma_f32_16x16x32_bf16(wf[ft][0], xf0, acc, 0, 0, 0);
          acc = __builtin_amdgcn_mfma_f32_16x16x32_bf16(wf[ft][1], xf1, acc, 0, 0, 0);
          *(f32x4*)(ob + ft * 16) = acc;
        }
        if (y < 15) { xf0 = pack8(t0, t1); xf1 = pack8(t2, t3); }
      }
    } else {
      const f32x4 z = {0.f, 0.f, 0.f, 0.f};
#pragma unroll 4
      for (int y = 0; y < 16; ++y) {
        float* ob = obase + y * (2 * 512 * 64);
#pragma unroll
        for (int ft = 0; ft < 4; ++ft)
          *(f32x4*)(ob + ft * 16) = z;
      }
    }
  }
}

extern "C" void kernel_launch(void* const* d_in, const int* in_sizes, int n_in,
                              void* d_out, int out_size, void* d_ws, size_t ws_size,
                              hipStream_t stream) {
  const float* in   = (const float*)d_in[0];
  const float* mask = (const float*)d_in[1];
  const float* kern = (const float*)d_in[2];
  const float* bias = (const float*)d_in[3];
  float* out = (float*)d_out;
  dim3 grid(1024), block(256);
  hipLaunchKernelGGL(sparse_deconv_kernel, grid, block, 0, stream,
                     in, mask, kern, bias, out);
}

// Round 4
// 150.869 us; speedup vs baseline: 1.4255x; 1.4255x over previous
//
#include <hip/hip_runtime.h>
#include <hip/hip_bf16.h>

typedef __attribute__((ext_vector_type(4))) float f32x4;
typedef __attribute__((ext_vector_type(8))) short s16x8;

__device__ inline short to_bf16(float f) {
  union { float f; unsigned u; } c; c.f = f;
  unsigned u = c.u;
  u += 0x7fffu + ((u >> 16) & 1u);   // round-to-nearest-even
  return (short)(u >> 16);
}

__device__ inline s16x8 pack8(f32x4 a, f32x4 b) {
  s16x8 r;
  r[0] = to_bf16(a[0]); r[1] = to_bf16(a[1]); r[2] = to_bf16(a[2]); r[3] = to_bf16(a[3]);
  r[4] = to_bf16(b[0]); r[5] = to_bf16(b[1]); r[6] = to_bf16(b[2]); r[7] = to_bf16(b[3]);
  return r;
}

// Explicit LDS ordering fence: drain all DS ops, pin compiler scheduling.
// (R3 raced without this — wave-private LDS write->read is NOT implicitly safe.)
__device__ inline void lds_fence() {
  asm volatile("s_waitcnt lgkmcnt(0)" ::: "memory");
  __builtin_amdgcn_sched_barrier(0);
}

// Wave = (input-row parity r, ky). Per slab s (2 input rows): wave loads input
// row y=2s+r once, computes its ky's two kx quadrants (8 m-tiles, 64 weight
// VGPRs), stages one 8KB output row in wave-private LDS (rotated slots), then
// stores it as 8 fully-contiguous 1KB dwordx4 instructions.
__global__ __launch_bounds__(256, 2)
void sparse_deconv_kernel(const float* __restrict__ in, const float* __restrict__ mask,
                          const float* __restrict__ kern, const float* __restrict__ bias,
                          float* __restrict__ out) {
  __shared__ float lds[4][2048];          // 8KB per wave, wave-private
  const int tid = threadIdx.x;
  const int w  = tid >> 6;
  const int l  = tid & 63;
  const int lm = l & 15;
  const int lg = l >> 4;
  const int r  = w & 1;                   // input row parity within slab
  const int ky = w >> 1;                  // output row parity (quadrant y)
  float* LB = &lds[w][0];

  // Weights for this wave's ky: global mt = ky*8 + kx*4 + ft (kernel flat [256][64])
  s16x8 wf[8][2];
#pragma unroll
  for (int m2 = 0; m2 < 8; ++m2) {
#pragma unroll
    for (int kf = 0; kf < 2; ++kf) {
      const float* p = kern + (((ky * 8 + m2) * 16 + lm) * 64 + kf * 32 + lg * 8);
      wf[m2][kf] = pack8(*(const f32x4*)p, *(const f32x4*)(p + 4));
    }
  }
  // bias frags: f = ft*16 + lg*4 + j
  f32x4 bv[4];
#pragma unroll
  for (int ft = 0; ft < 4; ++ft)
    bv[ft] = *(const f32x4*)(bias + ft * 16 + lg * 4);

  const int b  = blockIdx.x;   // 0..2047
  const int n  = b >> 8;
  const int by = (b >> 4) & 15;
  const int bx = b & 15;

  // per-block mask max (redundant per wave; no block barriers anywhere)
  const float* mp = mask + ((n * 256 + by * 16) * 256 + bx * 16);
  float mv = 0.0f;
#pragma unroll
  for (int i = 0; i < 4; ++i) {
    const int idx = i * 64 + l;
    mv = fmaxf(mv, mp[(idx >> 4) * 256 + (idx & 15)]);
  }
#pragma unroll
  for (int off = 32; off; off >>= 1)
    mv = fmaxf(mv, __shfl_xor(mv, off));
  const bool active = mv > 0.5f;

  const float* ibase = in + (((n * 256 + by * 16) * 256) + bx * 16 + lm) * 64 + lg * 8;
  float* oorigin = out + (((size_t)(n * 512 + by * 32)) * 512 + bx * 32) * 64;
  const int oyw = 2 * r + ky;             // wave's output row offset within a slab

  if (active) {
    f32x4 t0, t1, t2, t3;
    {
      const float* p = ibase + r * (256 * 64);
      t0 = *(const f32x4*)p;        t1 = *(const f32x4*)(p + 4);
      t2 = *(const f32x4*)(p + 32); t3 = *(const f32x4*)(p + 36);
    }
#pragma unroll
    for (int s = 0; s < 8; ++s) {
      // prefetch next slab's input row (global, vmcnt — unaffected by lds_fence)
      f32x4 u0, u1, u2, u3;
      if (s < 7) {
        const float* p = ibase + (2 * s + 2 + r) * (256 * 64);
        u0 = *(const f32x4*)p;        u1 = *(const f32x4*)(p + 4);
        u2 = *(const f32x4*)(p + 32); u3 = *(const f32x4*)(p + 36);
      }
      s16x8 xf0 = pack8(t0, t1), xf1 = pack8(t2, t3);

      lds_fence();   // WAR: previous slab's readback complete before overwrite
#pragma unroll
      for (int kx = 0; kx < 2; ++kx) {
#pragma unroll
        for (int ft = 0; ft < 4; ++ft) {
          f32x4 acc = bv[ft];
          acc = __builtin_amdgcn_mfma_f32_16x16x32_bf16(wf[kx * 4 + ft][0], xf0, acc, 0, 0, 0);
          acc = __builtin_amdgcn_mfma_f32_16x16x32_bf16(wf[kx * 4 + ft][1], xf1, acc, 0, 0, 0);
          const int p  = 2 * lm + kx;                // pixel 0..31
          const int sl = (4 * ft + lg + p) & 15;     // rotated fslot
          *(f32x4*)(LB + p * 64 + sl * 4) = acc;
        }
      }
      lds_fence();   // RAW: staging writes complete before readback

      {
        const int oy = 4 * s + oyw;
        float* orow = oorigin + (size_t)oy * (512 * 64) + l * 4;
#pragma unroll
        for (int rc = 0; rc < 8; ++rc) {
          const int p  = rc * 4 + lg;
          const int sl = (lm + p) & 15;
          f32x4 v = *(const f32x4*)(LB + p * 64 + sl * 4);
          *(f32x4*)(orow + rc * 256) = v;   // 64 lanes x 16B fully contiguous = 1KB/instr
        }
      }
      if (s < 7) { t0 = u0; t1 = u1; t2 = u2; t3 = u3; }
    }
  } else {
    const f32x4 z = {0.f, 0.f, 0.f, 0.f};
#pragma unroll
    for (int i = 0; i < 8; ++i) {
      float* orow = oorigin + (size_t)(w * 8 + i) * (512 * 64) + l * 4;
#pragma unroll
      for (int rc = 0; rc < 8; ++rc)
        *(f32x4*)(orow + rc * 256) = z;
    }
  }
}

extern "C" void kernel_launch(void* const* d_in, const int* in_sizes, int n_in,
                              void* d_out, int out_size, void* d_ws, size_t ws_size,
                              hipStream_t stream) {
  const float* in   = (const float*)d_in[0];
  const float* mask = (const float*)d_in[1];
  const float* kern = (const float*)d_in[2];
  const float* bias = (const float*)d_in[3];
  float* out = (float*)d_out;
  dim3 grid(2048), block(256);
  hipLaunchKernelGGL(sparse_deconv_kernel, grid, block, 0, stream,
                     in, mask, kern, bias, out);
}

// Round 5
// 130.755 us; speedup vs baseline: 1.6448x; 1.1538x over previous
//
#include <hip/hip_runtime.h>
#include <hip/hip_bf16.h>

typedef __attribute__((ext_vector_type(4))) float f32x4;
typedef __attribute__((ext_vector_type(8))) short s16x8;

// HW packed f32->bf16 (RTNE), 1 instr per 2 elements.
__device__ inline unsigned cvtpk(float a, float b) {
  unsigned r;
  asm("v_cvt_pk_bf16_f32 %0, %1, %2" : "=v"(r) : "v"(a), "v"(b));
  return r;
}
__device__ inline s16x8 pack8(f32x4 a, f32x4 b) {
  union { unsigned u[4]; s16x8 v; } x;
  x.u[0] = cvtpk(a[0], a[1]); x.u[1] = cvtpk(a[2], a[3]);
  x.u[2] = cvtpk(b[0], b[1]); x.u[3] = cvtpk(b[2], b[3]);
  return x.v;
}

// Explicit LDS RAW fence (R3 lesson: wave-private LDS write->read is NOT
// implicitly ordered; compiler can't prove rotated-slot aliasing).
__device__ inline void lds_fence() {
  asm volatile("s_waitcnt lgkmcnt(0)" ::: "memory");
  __builtin_amdgcn_sched_barrier(0);
}

// Wave = (input-row parity r, ky). Slab s: row y=2s+r -> output row 4s+2r+ky.
// LDS staging double-buffered (16KB/wave) -> single lgkmcnt fence per slab;
// input prefetched 2 slabs deep; stores fully contiguous 1KB/instr, nontemporal.
__global__ __launch_bounds__(256, 2)
void sparse_deconv_kernel(const float* __restrict__ in, const float* __restrict__ mask,
                          const float* __restrict__ kern, const float* __restrict__ bias,
                          float* __restrict__ out) {
  __shared__ float lds[4][2][2048];        // 16KB per wave, wave-private, dbuf
  const int tid = threadIdx.x;
  const int w  = tid >> 6;
  const int l  = tid & 63;
  const int lm = l & 15;
  const int lg = l >> 4;
  const int r  = w & 1;                    // input row parity within slab
  const int ky = w >> 1;                   // output row parity

  // Weights for this ky: mt = ky*8 + kx*4 + ft (kernel flat [256][64])
  s16x8 wf[8][2];
#pragma unroll
  for (int m2 = 0; m2 < 8; ++m2) {
#pragma unroll
    for (int kf = 0; kf < 2; ++kf) {
      const float* p = kern + (((ky * 8 + m2) * 16 + lm) * 64 + kf * 32 + lg * 8);
      wf[m2][kf] = pack8(*(const f32x4*)p, *(const f32x4*)(p + 4));
    }
  }
  f32x4 bv[4];
#pragma unroll
  for (int ft = 0; ft < 4; ++ft)
    bv[ft] = *(const f32x4*)(bias + ft * 16 + lg * 4);

  const int b  = blockIdx.x;   // 0..2047
  const int n  = b >> 8;
  const int by = (b >> 4) & 15;
  const int bx = b & 15;

  // per-block mask max (redundant per wave; no block barriers anywhere)
  const float* mp = mask + ((n * 256 + by * 16) * 256 + bx * 16);
  float mv = 0.0f;
#pragma unroll
  for (int i = 0; i < 4; ++i) {
    const int idx = i * 64 + l;
    mv = fmaxf(mv, mp[(idx >> 4) * 256 + (idx & 15)]);
  }
#pragma unroll
  for (int off = 32; off; off >>= 1)
    mv = fmaxf(mv, __shfl_xor(mv, off));
  const bool active = mv > 0.5f;

  const float* ibase = in + (((n * 256 + by * 16) * 256) + bx * 16 + lm) * 64 + lg * 8;
  float* oorigin = out + (((size_t)(n * 512 + by * 32)) * 512 + bx * 32) * 64;
  const int oyw = 2 * r + ky;

  if (active) {
    f32x4 tb[2][4];   // two rotating row buffers (fully unrolled -> static idx)
#pragma unroll
    for (int q = 0; q < 2; ++q) {
      const float* p = ibase + (2 * q + r) * (256 * 64);
      tb[q][0] = *(const f32x4*)p;        tb[q][1] = *(const f32x4*)(p + 4);
      tb[q][2] = *(const f32x4*)(p + 32); tb[q][3] = *(const f32x4*)(p + 36);
    }
#pragma unroll
    for (int s = 0; s < 8; ++s) {
      const int bsel = s & 1;
      s16x8 xf0 = pack8(tb[bsel][0], tb[bsel][1]);
      s16x8 xf1 = pack8(tb[bsel][2], tb[bsel][3]);
      if (s < 6) {   // prefetch 2 slabs ahead into the buffer just consumed
        const float* p = ibase + (2 * (s + 2) + r) * (256 * 64);
        tb[bsel][0] = *(const f32x4*)p;        tb[bsel][1] = *(const f32x4*)(p + 4);
        tb[bsel][2] = *(const f32x4*)(p + 32); tb[bsel][3] = *(const f32x4*)(p + 36);
      }
      float* LB = &lds[w][bsel][0];
#pragma unroll
      for (int kx = 0; kx < 2; ++kx) {
#pragma unroll
        for (int ft = 0; ft < 4; ++ft) {
          f32x4 acc = bv[ft];
          acc = __builtin_amdgcn_mfma_f32_16x16x32_bf16(wf[kx * 4 + ft][0], xf0, acc, 0, 0, 0);
          acc = __builtin_amdgcn_mfma_f32_16x16x32_bf16(wf[kx * 4 + ft][1], xf1, acc, 0, 0, 0);
          const int p  = 2 * lm + kx;                // pixel 0..31
          const int sl = (4 * ft + lg + p) & 15;     // rotated fslot
          *(f32x4*)(LB + p * 64 + sl * 4) = acc;
        }
      }
      lds_fence();   // RAW: this slab's staging writes complete before readback

      const int oy = 4 * s + oyw;
      float* orow = oorigin + (size_t)oy * (512 * 64) + l * 4;
#pragma unroll
      for (int rc = 0; rc < 8; ++rc) {
        const int p  = rc * 4 + lg;
        const int sl = (lm + p) & 15;
        f32x4 v = *(const f32x4*)(LB + p * 64 + sl * 4);
        __builtin_nontemporal_store(v, (f32x4*)(orow + rc * 256));  // 1KB/instr
      }
    }
  } else {
    const f32x4 z = {0.f, 0.f, 0.f, 0.f};
#pragma unroll
    for (int i = 0; i < 8; ++i) {
      float* orow = oorigin + (size_t)(w * 8 + i) * (512 * 64) + l * 4;
#pragma unroll
      for (int rc = 0; rc < 8; ++rc)
        __builtin_nontemporal_store(z, (f32x4*)(orow + rc * 256));
    }
  }
}

extern "C" void kernel_launch(void* const* d_in, const int* in_sizes, int n_in,
                              void* d_out, int out_size, void* d_ws, size_t ws_size,
                              hipStream_t stream) {
  const float* in   = (const float*)d_in[0];
  const float* mask = (const float*)d_in[1];
  const float* kern = (const float*)d_in[2];
  const float* bias = (const float*)d_in[3];
  float* out = (float*)d_out;
  dim3 grid(2048), block(256);
  hipLaunchKernelGGL(sparse_deconv_kernel, grid, block, 0, stream,
                     in, mask, kern, bias, out);
}